// Round 5
// baseline (230.733 us; speedup 1.0000x reference)
//
#include <hip/hip_runtime.h>

typedef __bf16 bf16;
typedef _Float16 f16;
typedef __bf16 bf16x8 __attribute__((ext_vector_type(8)));
typedef _Float16 f16x8 __attribute__((ext_vector_type(8)));
typedef _Float16 f16x4 __attribute__((ext_vector_type(4)));
typedef float f32x4 __attribute__((ext_vector_type(4)));

#define NROWS 4096
#define DIN 1024
#define DA 512

template <typename T> struct V8;
template <> struct V8<f16> { using type = f16x8; };
template <> struct V8<bf16> { using type = bf16x8; };

__device__ __forceinline__ f32x4 mfma16(f16x8 a, f16x8 b, f32x4 c) {
  return __builtin_amdgcn_mfma_f32_16x16x32_f16(a, b, c, 0, 0, 0);
}
__device__ __forceinline__ f32x4 mfma16(bf16x8 a, bf16x8 b, f32x4 c) {
  return __builtin_amdgcn_mfma_f32_16x16x32_bf16(a, b, c, 0, 0, 0);
}

__device__ __forceinline__ void gload_lds16(const void* g, void* l) {
  __builtin_amdgcn_global_load_lds((const __attribute__((address_space(1))) void*)g,
                                   (__attribute__((address_space(3))) void*)l, 16, 0, 0);
}

// ---------------- prep kernels ----------------

__global__ void cast_kernel(const float* __restrict__ s1, const float* __restrict__ s2,
                            f16* __restrict__ d1, f16* __restrict__ d2, int n) {
  const float* s = blockIdx.z ? s2 : s1;
  f16* d = blockIdx.z ? d2 : d1;
  int i = (blockIdx.x * blockDim.x + threadIdx.x) * 4;
  if (i < n) {
    float4 v = *(const float4*)(s + i);
    f16x4 o;
    o[0] = (f16)v.x; o[1] = (f16)v.y; o[2] = (f16)v.z; o[3] = (f16)v.w;
    *(f16x4*)(d + i) = o;
  }
}

// dst[c][r] = (f16) src[r][c]
__global__ void transpose_f32(const float* __restrict__ w0, const float* __restrict__ w1,
                              const float* __restrict__ w2, f16* __restrict__ dst,
                              size_t dstride, int rows, int cols) {
  const float* s = blockIdx.z == 0 ? w0 : (blockIdx.z == 1 ? w1 : w2);
  f16* d = dst + (size_t)blockIdx.z * dstride;
  __shared__ float tile[32][33];
  int bc = blockIdx.x * 32, br = blockIdx.y * 32;
  int tx = threadIdx.x, ty = threadIdx.y;
  for (int i = ty; i < 32; i += 8)
    tile[i][tx] = s[(size_t)(br + i) * cols + bc + tx];
  __syncthreads();
  for (int i = ty; i < 32; i += 8)
    d[(size_t)(bc + i) * rows + br + tx] = (f16)tile[tx][i];
}

// bf16 [rows,cols] -> bf16 [cols][rows]
__global__ void transpose_b16(const bf16* __restrict__ src, size_t sstride,
                              bf16* __restrict__ dst, size_t dstride, int rows, int cols) {
  const bf16* s = src + (size_t)blockIdx.z * sstride;
  bf16* d = dst + (size_t)blockIdx.z * dstride;
  __shared__ float tile[32][33];
  int bc = blockIdx.x * 32, br = blockIdx.y * 32;
  int tx = threadIdx.x, ty = threadIdx.y;
  for (int i = ty; i < 32; i += 8)
    tile[i][tx] = (float)s[(size_t)(br + i) * cols + bc + tx];
  __syncthreads();
  for (int i = ty; i < 32; i += 8)
    d[(size_t)(bc + i) * rows + br + tx] = (bf16)tile[tx][i];
}

// merge 4 KV-chunk partials: mid = sum(pO[slot]) / sum(prs[slot]), f16
__global__ void merge_kernel(const float* __restrict__ pO, const float* __restrict__ prs,
                             f16* __restrict__ mid) {
  const size_t QS = (size_t)NROWS * DA;
  size_t e = ((size_t)blockIdx.x * blockDim.x + threadIdx.x) * 4;
  int z = (int)(e / QS);
  size_t rem = e - (size_t)z * QS;
  int row = (int)(rem / DA);
  float ax = 0, ay = 0, az = 0, aw = 0, rs = 0;
#pragma unroll
  for (int cc = 0; cc < 4; ++cc) {
    int slot = cc * 2 + z;
    float4 a = *(const float4*)(pO + (size_t)slot * QS + rem);
    ax += a.x; ay += a.y; az += a.z; aw += a.w;
    rs += prs[slot * NROWS + row];
  }
  float inv = 1.0f / rs;
  f16x4 o;
  o[0] = (f16)(ax * inv); o[1] = (f16)(ay * inv);
  o[2] = (f16)(az * inv); o[3] = (f16)(aw * inv);
  *(f16x4*)(mid + e) = o;
}

// ---------------- fused attention ----------------
// grid 512 1-D: flat -> slot(=chunk*2+z) = flat&7 (pins (chunk,z) KV to one XCD),
// qb = flat>>3. Block: 64 Q-rows, 8 waves (4 row-groups x 2 col-halves).
// Per 128-KV tile: S=Q@K^T (K dbuf-staged, XOR-swizzled), P=exp(S)->LDS,
// rowsum via ones-MFMA, O += P@V (Vt dbuf-staged). Partials f32 -> pO/prs.

__global__ __launch_bounds__(512, 2) void fused_attn(
    const f16* __restrict__ q1, const f16* __restrict__ k1,
    const f16* __restrict__ q2, const f16* __restrict__ k2,
    const bf16* __restrict__ v1t, const bf16* __restrict__ v2t,
    float* __restrict__ pO, float* __restrict__ prs) {
  __shared__ __align__(16) char smem[81920];  // K dbuf 32K / V dbuf 64K (union) + P 16K
  const int flat = blockIdx.x;
  const int slot = flat & 7;
  const int z = slot & 1;
  const int chunk = slot >> 1;
  const int qb = flat >> 3;  // 0..63
  const f16* __restrict__ Q = z ? q2 : q1;
  const f16* __restrict__ Kp = z ? k1 : k2;
  const bf16* __restrict__ Vt = z ? v1t : v2t;
  const int kv0 = chunk * 1024;

  const int tid = threadIdx.x, w = tid >> 6, lane = tid & 63;
  const int r = w >> 1, c = w & 1;
  const int lr = lane & 15, lh = lane >> 4;

  // Q fragments: 16 K-slices of 32, A-frag layout (row=lr, k=lh*8+j)
  f16x8 qf[16];
  {
    const f16* qp = Q + (size_t)(qb * 64 + r * 16 + lr) * DA + lh * 8;
#pragma unroll
    for (int s = 0; s < 16; ++s) qf[s] = *(const f16x8*)(qp + s * 32);
  }

  f32x4 o[16] = {};
  f32x4 rsacc = {};
  bf16x8 ones;
#pragma unroll
  for (int i = 0; i < 8; ++i) ones[i] = (bf16)1.0f;

  char* const Pb = smem + 65536;

  for (int kvt = 0; kvt < 8; ++kvt) {
    const int kvbase = kv0 + kvt * 128;
    f32x4 s4[4] = {};

    // stage K slice 0 -> Kb0 (source-side XOR swizzle: chunk ^= row&7)
#pragma unroll
    for (int it = 0; it < 2; ++it) {
      int cidx = (it * 8 + w) * 64 + lane;
      int row = cidx >> 3, cc = cidx & 7;
      gload_lds16(Kp + (size_t)(kvbase + row) * DA + (cc ^ (row & 7)) * 8,
                  smem + cidx * 16);
    }
    __syncthreads();

#pragma unroll
    for (int kd = 0; kd < 8; ++kd) {
      char* cur = smem + (kd & 1) * 16384;
      if (kd < 7) {
        char* nxt = smem + ((kd + 1) & 1) * 16384;
#pragma unroll
        for (int it = 0; it < 2; ++it) {
          int cidx = (it * 8 + w) * 64 + lane;
          int row = cidx >> 3, cc = cidx & 7;
          gload_lds16(Kp + (size_t)(kvbase + row) * DA + (kd + 1) * 64 + (cc ^ (row & 7)) * 8,
                      nxt + cidx * 16);
        }
      }
#pragma unroll
      for (int n = 0; n < 4; ++n) {
        int row = c * 64 + n * 16 + lr;
#pragma unroll
        for (int kk = 0; kk < 2; ++kk) {
          f16x8 bf = *(const f16x8*)(cur + row * 128 + ((kk * 4 + lh) ^ (row & 7)) * 16);
          s4[n] = mfma16(qf[kd * 2 + kk], bf, s4[n]);
        }
      }
      __syncthreads();
    }

    // stage V pair {0,4} -> Vb0 (overlaps K region; safe: all waves past barrier)
#pragma unroll
    for (int it = 0; it < 4; ++it) {
      int cidx = (it * 8 + w) * 64 + lane;
      int half = cidx >> 10, ci = cidx & 1023;
      int row = ci >> 4, cc = ci & 15;
      gload_lds16(Vt + (size_t)((half * 4) * 64 + row) * NROWS + kvbase + (cc ^ (row & 7)) * 8,
                  smem + cidx * 16);
    }

    // exp + P write (swizzled byte: ^ (row&7)<<4)
#pragma unroll
    for (int n = 0; n < 4; ++n) {
      int col = c * 64 + n * 16 + lr;
#pragma unroll
      for (int rr = 0; rr < 4; ++rr) {
        int row = r * 16 + lh * 4 + rr;
        int byte = (row * 256 + col * 2) ^ ((row & 7) << 4);
        *(bf16*)(Pb + byte) = (bf16)__expf(s4[n][rr]);
      }
    }
    __syncthreads();  // P visible + V pair 0 staged

    // read P A-frags (bf16), rowsum via ones-MFMA (c==0 waves only)
    bf16x8 pa[4];
#pragma unroll
    for (int s = 0; s < 4; ++s) {
      int row = r * 16 + lr;
      int byte = (row * 256 + (s * 32 + lh * 8) * 2) ^ ((row & 7) << 4);
      pa[s] = *(const bf16x8*)(Pb + byte);
    }
    if (c == 0) {
#pragma unroll
      for (int s = 0; s < 4; ++s) rsacc = mfma16(pa[s], ones, rsacc);
    }

    // PV: j = output-col slice pairs; wave-half c reads its 16K half
#pragma unroll
    for (int j = 0; j < 4; ++j) {
      char* cur = smem + (j & 1) * 32768 + c * 16384;
      if (j < 3) {
        char* nxt = smem + ((j + 1) & 1) * 32768;
#pragma unroll
        for (int it = 0; it < 4; ++it) {
          int cidx = (it * 8 + w) * 64 + lane;
          int half = cidx >> 10, ci = cidx & 1023;
          int row = ci >> 4, cc = ci & 15;
          gload_lds16(Vt + (size_t)((j + 1 + half * 4) * 64 + row) * NROWS + kvbase + (cc ^ (row & 7)) * 8,
                      nxt + cidx * 16);
        }
      }
#pragma unroll
      for (int n2 = 0; n2 < 4; ++n2) {
        int row = n2 * 16 + lr;
#pragma unroll
        for (int s = 0; s < 4; ++s) {
          bf16x8 vf = *(const bf16x8*)(cur + row * 256 + ((s * 4 + lh) ^ (row & 7)) * 16);
          o[j * 4 + n2] = mfma16(pa[s], vf, o[j * 4 + n2]);
        }
      }
      __syncthreads();
    }
  }

  // epilogue: write f32 partial O and rowsum
  const size_t obase = (size_t)slot * ((size_t)NROWS * DA);
#pragma unroll
  for (int t = 0; t < 16; ++t) {
#pragma unroll
    for (int rr = 0; rr < 4; ++rr) {
      int row = qb * 64 + r * 16 + lh * 4 + rr;
      int col = c * 256 + t * 16 + lr;
      pO[obase + (size_t)row * DA + col] = o[t][rr];
    }
  }
  if (c == 0 && lr == 0) {
#pragma unroll
    for (int rr = 0; rr < 4; ++rr)
      prs[slot * NROWS + qb * 64 + r * 16 + lh * 4 + rr] = rsacc[rr];
  }
}

// ---------------- GEMM (proj / out) ----------------

template <typename TIN>
struct GArgs {
  const TIN* A[6];
  const TIN* B[6];
  const float* bias[6];
  void* C[6];
  int storebf[6];
  int K, lda, ldb, ldc;
};

// EPI 0: +bias, store f16/bf16 per storebf[z];  EPI 3: +bias, store f32
template <typename TIN, typename TOUT, int EPI>
__global__ __launch_bounds__(512) void gemm_bt(GArgs<TIN> args) {
  using vec8 = typename V8<TIN>::type;
  __shared__ __align__(16) TIN As[128 * 64];
  __shared__ __align__(16) TIN Bs[128 * 64];

  const int z = blockIdx.z;
  const TIN* __restrict__ Ag = args.A[z];
  const TIN* __restrict__ Bg = args.B[z];
  const float* __restrict__ bias = args.bias[z];
  void* Cg = args.C[z];
  const int K = args.K;
  const int lda = args.lda, ldb = args.ldb, ldc = args.ldc;

  int blkM, blkN;
  {
    const int gx = gridDim.x;
    const int nwg = gx * gridDim.y;
    const int lin = blockIdx.y * gx + blockIdx.x;
    if ((nwg & 7) == 0) {
      const int q = nwg >> 3;
      const int nl = (lin & 7) * q + (lin >> 3);
      blkN = nl % gx;
      blkM = nl / gx;
    } else {
      blkN = blockIdx.x;
      blkM = blockIdx.y;
    }
  }

  const int tid = threadIdx.x;
  const int w = tid >> 6, lane = tid & 63;
  const int wr = w >> 2, wc = w & 3;
  const int lrow = lane & 15, lhi = lane >> 4;

  const TIN* Abase = Ag + (size_t)blkM * 128 * lda;
  const TIN* Bbase = Bg + (size_t)blkN * 128 * ldb;

  f32x4 acc[4][2] = {};

  for (int kt = 0; kt < K; kt += 64) {
#pragma unroll
    for (int it = 0; it < 2; ++it) {
      int grp = it * 8 + w;
      int chunk = grp * 64 + lane;
      int row = chunk >> 3;
      int col = (chunk & 7) << 3;
      gload_lds16(Abase + (size_t)row * lda + kt + col, (char*)As + (size_t)grp * 1024);
      gload_lds16(Bbase + (size_t)row * ldb + kt + col, (char*)Bs + (size_t)grp * 1024);
    }
    __syncthreads();

    vec8 af[4][2], bfr[2][2];
#pragma unroll
    for (int m = 0; m < 4; ++m)
#pragma unroll
      for (int kk = 0; kk < 2; ++kk)
        af[m][kk] = *(const vec8*)&As[(wr * 64 + m * 16 + lrow) * 64 + kk * 32 + lhi * 8];
#pragma unroll
    for (int n = 0; n < 2; ++n)
#pragma unroll
      for (int kk = 0; kk < 2; ++kk)
        bfr[n][kk] = *(const vec8*)&Bs[(wc * 32 + n * 16 + lrow) * 64 + kk * 32 + lhi * 8];

#pragma unroll
    for (int m = 0; m < 4; ++m)
#pragma unroll
      for (int n = 0; n < 2; ++n)
#pragma unroll
        for (int kk = 0; kk < 2; ++kk)
          acc[m][n] = mfma16(af[m][kk], bfr[n][kk], acc[m][n]);
    __syncthreads();
  }

  const int row0 = blkM * 128 + wr * 64;
  const int col0 = blkN * 128 + wc * 32;
  const int sbf = args.storebf[z];
#pragma unroll
  for (int m = 0; m < 4; ++m) {
#pragma unroll
    for (int n = 0; n < 2; ++n) {
#pragma unroll
      for (int r = 0; r < 4; ++r) {
        int row = row0 + m * 16 + lhi * 4 + r;
        int col = col0 + n * 16 + lrow;
        float v = acc[m][n][r] + bias[col];
        if (EPI == 0) {
          if (sbf)
            ((bf16*)Cg)[(size_t)row * ldc + col] = (bf16)v;
          else
            ((f16*)Cg)[(size_t)row * ldc + col] = (f16)v;
        } else {
          ((float*)Cg)[(size_t)row * ldc + col] = v;
        }
      }
    }
  }
}

// ---------------- launch ----------------

extern "C" void kernel_launch(void* const* d_in, const int* in_sizes, int n_in,
                              void* d_out, int out_size, void* d_ws, size_t ws_size,
                              hipStream_t stream) {
  const float* in1 = (const float*)d_in[0];
  const float* in2 = (const float*)d_in[1];
  const float* Wq = (const float*)d_in[2];
  const float* bq = (const float*)d_in[3];
  const float* Wk = (const float*)d_in[4];
  const float* bk = (const float*)d_in[5];
  const float* Wv = (const float*)d_in[6];
  const float* bv = (const float*)d_in[7];
  const float* Wo = (const float*)d_in[8];
  const float* bo = (const float*)d_in[9];
  float* out = (float*)d_out;

  const size_t IN_E = (size_t)NROWS * DIN;  // 4M
  const size_t WT_E = (size_t)DA * DIN;     // 512K
  const size_t QS = (size_t)NROWS * DA;     // 2M

  char* base = (char*)d_ws;
  f16* qk = (f16*)(base);                        // 16 MB: Q1,K1,Q2,K2 [live thru fused]
  bf16* vt = (bf16*)(base + (16ull << 20));      // 8 MB: V1t,V2t [live thru fused]
  f16* woT = (f16*)(base + (24ull << 20));       // 1 MB [live thru out-GEMM]
  f16* mid = (f16*)(base + (25ull << 20));       // 8 MB [merge -> out]
  f16* in_hf = (f16*)(base + (33ull << 20));     // 16 MB [dead after proj]
  bf16* vv = (bf16*)(base + (49ull << 20));      // 8 MB [dead after vt transpose]
  f16* wt = (f16*)(base + (57ull << 20));        // 3 MB [dead after proj]
  float* pO = (float*)(base + (33ull << 20));    // 64 MB [fused -> merge], aliases dead bufs
  float* prs = (float*)(base + (97ull << 20));   // 128 KB

  // 1. cast inputs to fp16
  cast_kernel<<<dim3((unsigned)(IN_E / 1024), 1, 2), dim3(256), 0, stream>>>(
      in1, in2, in_hf, in_hf + IN_E, (int)IN_E);

  // 2. transpose-cast weights
  transpose_f32<<<dim3(DA / 32, DIN / 32, 3), dim3(32, 8), 0, stream>>>(
      Wq, Wk, Wv, wt, WT_E, DIN, DA);
  transpose_f32<<<dim3(DIN / 32, DA / 32, 1), dim3(32, 8), 0, stream>>>(
      Wo, Wo, Wo, woT, 0, DA, DIN);

  // 3. projections, z = Q1,K1,Q2,K2,V1,V2 (V stored bf16)
  {
    GArgs<f16> a{};
    const float* bs[3] = {bq, bk, bv};
    for (int zi = 0; zi < 6; ++zi) {
      int which = (zi < 4) ? (zi & 1) : 2;
      int src = (zi < 4) ? (zi >> 1) : (zi - 4);
      a.A[zi] = in_hf + (size_t)src * IN_E;
      a.B[zi] = wt + (size_t)which * WT_E;
      a.bias[zi] = bs[which];
      a.C[zi] = (zi < 4) ? (void*)(qk + (size_t)zi * QS) : (void*)(vv + (size_t)(zi - 4) * QS);
      a.storebf[zi] = (zi >= 4);
    }
    a.K = DIN; a.lda = DIN; a.ldb = DIN; a.ldc = DA;
    gemm_bt<f16, f16, 0><<<dim3(DA / 128, NROWS / 128, 6), dim3(512), 0, stream>>>(a);
  }

  // 4. V -> Vt ([4096,512] -> [512][4096])
  transpose_b16<<<dim3(DA / 32, NROWS / 32, 2), dim3(32, 8), 0, stream>>>(
      vv, QS, vt, QS, NROWS, DA);

  // 5. fused attention -> pO/prs partials (4 KV chunks x 2 z x 64 Q-blocks)
  fused_attn<<<dim3(512), dim3(512), 0, stream>>>(
      qk + 0 * QS, qk + 1 * QS, qk + 2 * QS, qk + 3 * QS,
      vt, vt + QS, pO, prs);

  // 6. merge partials -> mid (f16)
  merge_kernel<<<dim3((unsigned)(2 * QS / 1024)), dim3(256), 0, stream>>>(pO, prs, mid);

  // 7. out = mid @ Wo + bo (f32)
  {
    GArgs<f16> a{};
    a.A[0] = mid;      a.C[0] = out;
    a.A[1] = mid + QS; a.C[1] = out + (size_t)NROWS * DIN;
    a.B[0] = a.B[1] = woT;
    a.bias[0] = a.bias[1] = bo;
    a.K = DA; a.lda = DA; a.ldb = DA; a.ldc = DIN;
    gemm_bt<f16, float, 3><<<dim3(DIN / 128, NROWS / 128, 2), dim3(512), 0, stream>>>(a);
  }
}

// Round 6
// 230.342 us; speedup vs baseline: 1.0017x; 1.0017x over previous
//
#include <hip/hip_runtime.h>

typedef __bf16 bf16;
typedef _Float16 f16;
typedef __bf16 bf16x8 __attribute__((ext_vector_type(8)));
typedef _Float16 f16x8 __attribute__((ext_vector_type(8)));
typedef _Float16 f16x4 __attribute__((ext_vector_type(4)));
typedef float f32x4 __attribute__((ext_vector_type(4)));

#define NROWS 4096
#define DIN 1024
#define DA 512

template <typename T> struct V8;
template <> struct V8<f16> { using type = f16x8; };
template <> struct V8<bf16> { using type = bf16x8; };

__device__ __forceinline__ f32x4 mfma16(f16x8 a, f16x8 b, f32x4 c) {
  return __builtin_amdgcn_mfma_f32_16x16x32_f16(a, b, c, 0, 0, 0);
}
__device__ __forceinline__ f32x4 mfma16(bf16x8 a, bf16x8 b, f32x4 c) {
  return __builtin_amdgcn_mfma_f32_16x16x32_bf16(a, b, c, 0, 0, 0);
}

__device__ __forceinline__ void gload_lds16(const void* g, void* l) {
  __builtin_amdgcn_global_load_lds((const __attribute__((address_space(1))) void*)g,
                                   (__attribute__((address_space(3))) void*)l, 16, 0, 0);
}

__device__ __forceinline__ void nt_store_bf16(float v, bf16* p) {
  union { bf16 b; unsigned short u; } c;
  c.b = (bf16)v;
  __builtin_nontemporal_store(c.u, (unsigned short*)p);
}
__device__ __forceinline__ void nt_store_f16(float v, f16* p) {
  union { f16 h; unsigned short u; } c;
  c.h = (f16)v;
  __builtin_nontemporal_store(c.u, (unsigned short*)p);
}

// ---------------- prep kernels ----------------

__global__ void cast_kernel(const float* __restrict__ s1, const float* __restrict__ s2,
                            f16* __restrict__ d1, f16* __restrict__ d2, int n) {
  const float* s = blockIdx.z ? s2 : s1;
  f16* d = blockIdx.z ? d2 : d1;
  int i = (blockIdx.x * blockDim.x + threadIdx.x) * 4;
  if (i < n) {
    float4 v = *(const float4*)(s + i);
    f16x4 o;
    o[0] = (f16)v.x; o[1] = (f16)v.y; o[2] = (f16)v.z; o[3] = (f16)v.w;
    *(f16x4*)(d + i) = o;
  }
}

// dst[c][r] = (f16) src[r][c]
__global__ void transpose_f32(const float* __restrict__ w0, const float* __restrict__ w1,
                              const float* __restrict__ w2, f16* __restrict__ dst,
                              size_t dstride, int rows, int cols) {
  const float* s = blockIdx.z == 0 ? w0 : (blockIdx.z == 1 ? w1 : w2);
  f16* d = dst + (size_t)blockIdx.z * dstride;
  __shared__ float tile[32][33];
  int bc = blockIdx.x * 32, br = blockIdx.y * 32;
  int tx = threadIdx.x, ty = threadIdx.y;
  for (int i = ty; i < 32; i += 8)
    tile[i][tx] = s[(size_t)(br + i) * cols + bc + tx];
  __syncthreads();
  for (int i = ty; i < 32; i += 8)
    d[(size_t)(bc + i) * rows + br + tx] = (f16)tile[tx][i];
}

// bf16 [rows,cols] -> bf16 [cols][rows]
__global__ void transpose_b16(const bf16* __restrict__ src, size_t sstride,
                              bf16* __restrict__ dst, size_t dstride, int rows, int cols) {
  const bf16* s = src + (size_t)blockIdx.z * sstride;
  bf16* d = dst + (size_t)blockIdx.z * dstride;
  __shared__ float tile[32][33];
  int bc = blockIdx.x * 32, br = blockIdx.y * 32;
  int tx = threadIdx.x, ty = threadIdx.y;
  for (int i = ty; i < 32; i += 8)
    tile[i][tx] = (float)s[(size_t)(br + i) * cols + bc + tx];
  __syncthreads();
  for (int i = ty; i < 32; i += 8)
    d[(size_t)(bc + i) * rows + br + tx] = (bf16)tile[tx][i];
}

// merge split-K PV partials: mid = (pO[z]+pO[2+z]) / (rs[z]+rs[2+z]), f16
__global__ void merge_kernel(const float* __restrict__ pO, const float* __restrict__ prs,
                             f16* __restrict__ mid) {
  const size_t QS = (size_t)NROWS * DA;
  size_t e = ((size_t)blockIdx.x * blockDim.x + threadIdx.x) * 4;
  int z = (int)(e / QS);
  size_t rem = e - (size_t)z * QS;
  int row = (int)(rem / DA);
  f32x4 a = __builtin_nontemporal_load((const f32x4*)(pO + (size_t)z * QS + rem));
  f32x4 b = __builtin_nontemporal_load((const f32x4*)(pO + (size_t)(2 + z) * QS + rem));
  float rs = prs[z * NROWS + row] + prs[(2 + z) * NROWS + row];
  float inv = 1.0f / rs;
  f16x4 o;
  o[0] = (f16)((a[0] + b[0]) * inv);
  o[1] = (f16)((a[1] + b[1]) * inv);
  o[2] = (f16)((a[2] + b[2]) * inv);
  o[3] = (f16)((a[3] + b[3]) * inv);
  *(f16x4*)(mid + (size_t)z * QS + rem) = o;
}

// ---------------- GEMM ----------------
// C[M,N] = A[M,K_len] @ Bt[N,K_len]^T  (K window [k0, k0+K)), 128xNB tile, BK=64,
// 8 waves (2 row x 4 col, each 64 x NB/4), 16x16x32 MFMA, T1 XCD swizzle.
// EPI 0: +bias, store f16/bf16 per storebf[z]
// EPI 1: exp(), nt-store bf16
// EPI 2: split-K partial: nt-store f32 acc, nt-store partial rowsum
// EPI 3: +bias, nt-store f32

template <typename TIN>
struct GArgs {
  const TIN* A[6];
  const TIN* B[6];
  const float* bias[6];
  void* C[6];
  float* rsO[6];
  int k0[6];
  int storebf[6];
  int K, lda, ldb, ldc;
};

template <typename TIN, typename TOUT, int EPI, int NB>
__global__ __launch_bounds__(512) void gemm_bt(GArgs<TIN> args) {
  using vec8 = typename V8<TIN>::type;
  constexpr int NFR = NB / 64;   // n-fragments per wave
  constexpr int BIT = NB / 64;   // B staging iterations
  __shared__ __align__(16) TIN As[128 * 64];
  __shared__ __align__(16) TIN Bs[NB * 64];

  const int z = blockIdx.z;
  const TIN* __restrict__ Ag = args.A[z];
  const TIN* __restrict__ Bg = args.B[z];
  const float* __restrict__ bias = args.bias[z];
  void* Cg = args.C[z];
  const int K = args.K, k0 = args.k0[z];
  const int lda = args.lda, ldb = args.ldb, ldc = args.ldc;

  // T1: XCD-aware bijective swizzle (grids here are all %8==0)
  int blkM, blkN;
  {
    const int gx = gridDim.x;
    const int nwg = gx * gridDim.y;
    const int lin = blockIdx.y * gx + blockIdx.x;
    if ((nwg & 7) == 0) {
      const int q = nwg >> 3;
      const int nl = (lin & 7) * q + (lin >> 3);
      blkN = nl % gx;
      blkM = nl / gx;
    } else {
      blkN = blockIdx.x;
      blkM = blockIdx.y;
    }
  }

  const int tid = threadIdx.x;
  const int w = tid >> 6, lane = tid & 63;
  const int wr = w >> 2, wc = w & 3;
  const int lrow = lane & 15, lhi = lane >> 4;

  const TIN* Abase = Ag + (size_t)blkM * 128 * lda;
  const TIN* Bbase = Bg + (size_t)blkN * NB * ldb;

  f32x4 acc[4][NFR] = {};
  f32x4 rs[4] = {};
  vec8 ones;
  if (EPI == 2) {
#pragma unroll
    for (int i = 0; i < 8; ++i) ones[i] = (TIN)1.0f;
  }

  for (int kt = k0; kt < k0 + K; kt += 64) {
#pragma unroll
    for (int it = 0; it < 2; ++it) {
      int cidx = (it * 8 + w) * 64 + lane;  // 16B chunk index
      int row = cidx >> 3;
      int col = (cidx & 7) << 3;
      gload_lds16(Abase + (size_t)row * lda + kt + col, (char*)As + (size_t)cidx * 16);
    }
#pragma unroll
    for (int it = 0; it < BIT; ++it) {
      int cidx = (it * 8 + w) * 64 + lane;
      int row = cidx >> 3;
      int col = (cidx & 7) << 3;
      gload_lds16(Bbase + (size_t)row * ldb + kt + col, (char*)Bs + (size_t)cidx * 16);
    }
    __syncthreads();

    vec8 af[4][2], bfr[NFR][2];
#pragma unroll
    for (int m = 0; m < 4; ++m)
#pragma unroll
      for (int kk = 0; kk < 2; ++kk)
        af[m][kk] = *(const vec8*)&As[(wr * 64 + m * 16 + lrow) * 64 + kk * 32 + lhi * 8];
#pragma unroll
    for (int n = 0; n < NFR; ++n)
#pragma unroll
      for (int kk = 0; kk < 2; ++kk)
        bfr[n][kk] = *(const vec8*)&Bs[(wc * (NB / 4) + n * 16 + lrow) * 64 + kk * 32 + lhi * 8];

#pragma unroll
    for (int m = 0; m < 4; ++m)
#pragma unroll
      for (int n = 0; n < NFR; ++n)
#pragma unroll
        for (int kk = 0; kk < 2; ++kk)
          acc[m][n] = mfma16(af[m][kk], bfr[n][kk], acc[m][n]);

    if (EPI == 2 && wc == 0) {
#pragma unroll
      for (int m = 0; m < 4; ++m)
#pragma unroll
        for (int kk = 0; kk < 2; ++kk)
          rs[m] = mfma16(af[m][kk], ones, rs[m]);
    }
    __syncthreads();
  }

  const int row0 = blkM * 128 + wr * 64;
  const int col0 = blkN * NB + wc * (NB / 4);
  const int sbf = args.storebf[z];
#pragma unroll
  for (int m = 0; m < 4; ++m) {
#pragma unroll
    for (int n = 0; n < NFR; ++n) {
#pragma unroll
      for (int r = 0; r < 4; ++r) {
        int row = row0 + m * 16 + lhi * 4 + r;
        int col = col0 + n * 16 + lrow;
        float v = acc[m][n][r];
        if (EPI == 0) {
          if (sbf)
            ((bf16*)Cg)[(size_t)row * ldc + col] = (bf16)(v + bias[col]);
          else
            ((f16*)Cg)[(size_t)row * ldc + col] = (f16)(v + bias[col]);
        } else if (EPI == 1) {
          nt_store_bf16(__expf(v), &((bf16*)Cg)[(size_t)row * ldc + col]);
        } else if (EPI == 2) {
          __builtin_nontemporal_store(v, &((float*)Cg)[(size_t)row * ldc + col]);
        } else {
          __builtin_nontemporal_store(v + bias[col], &((float*)Cg)[(size_t)row * ldc + col]);
        }
      }
    }
  }
  if (EPI == 2 && wc == 0 && lrow == 0) {
    float* rsO = args.rsO[z];
#pragma unroll
    for (int m = 0; m < 4; ++m)
#pragma unroll
      for (int r = 0; r < 4; ++r)
        __builtin_nontemporal_store(rs[m][r], &rsO[row0 + m * 16 + lhi * 4 + r]);
  }
}

// ---------------- launch ----------------

extern "C" void kernel_launch(void* const* d_in, const int* in_sizes, int n_in,
                              void* d_out, int out_size, void* d_ws, size_t ws_size,
                              hipStream_t stream) {
  const float* in1 = (const float*)d_in[0];
  const float* in2 = (const float*)d_in[1];
  const float* Wq = (const float*)d_in[2];
  const float* bq = (const float*)d_in[3];
  const float* Wk = (const float*)d_in[4];
  const float* bk = (const float*)d_in[5];
  const float* Wv = (const float*)d_in[6];
  const float* bv = (const float*)d_in[7];
  const float* Wo = (const float*)d_in[8];
  const float* bo = (const float*)d_in[9];
  float* out = (float*)d_out;

  const size_t IN_E = (size_t)NROWS * DIN;   // 4M
  const size_t WT_E = (size_t)DA * DIN;      // 512K
  const size_t QS = (size_t)NROWS * DA;      // 2M
  const size_t PS = (size_t)NROWS * NROWS;   // 16M

  f16* qk = (f16*)d_ws;                      // 4*QS f16 = 16 MB (dead after QK GEMM)
  f16* in_hf = qk + 4 * QS;                  // 2*IN_E f16 = 16 MB (dead after proj)
  bf16* vv = (bf16*)(in_hf + 2 * IN_E);      // 2*QS bf16 = 8 MB (dead after transpose)
  f16* wt = (f16*)(vv + 2 * QS);             // 3*WT_E f16 = 3 MB
  f16* woT = wt + 3 * WT_E;                  // WT_E f16 = 1 MB (live till end)
  bf16* vt = (bf16*)(woT + WT_E);            // 2*QS bf16 = 8 MB
  bf16* P = vt + 2 * QS;                     // 2*PS bf16 = 64 MB
  f16* mid = (f16*)(P + 2 * PS);             // 2*QS f16 = 8 MB
  float* pO = (float*)d_ws;                  // aliases qk+in_hf: 4*QS f32 = 32 MB
  float* prs = (float*)vv;                   // aliases vv: 4*NROWS f32 = 64 KB

  // 1. cast inputs to fp16
  cast_kernel<<<dim3((unsigned)(IN_E / 1024), 1, 2), dim3(256), 0, stream>>>(
      in1, in2, in_hf, in_hf + IN_E, (int)IN_E);

  // 2. transpose-cast weights
  transpose_f32<<<dim3(DA / 32, DIN / 32, 3), dim3(32, 8), 0, stream>>>(
      Wq, Wk, Wv, wt, WT_E, DIN, DA);
  transpose_f32<<<dim3(DIN / 32, DA / 32, 1), dim3(32, 8), 0, stream>>>(
      Wo, Wo, Wo, woT, 0, DA, DIN);

  // 3. projections, z = Q1,K1,Q2,K2,V1,V2 (V stored bf16)
  {
    GArgs<f16> a{};
    const float* bs[3] = {bq, bk, bv};
    for (int zi = 0; zi < 6; ++zi) {
      int which = (zi < 4) ? (zi & 1) : 2;
      int src = (zi < 4) ? (zi >> 1) : (zi - 4);
      a.A[zi] = in_hf + (size_t)src * IN_E;
      a.B[zi] = wt + (size_t)which * WT_E;
      a.bias[zi] = bs[which];
      a.C[zi] = (zi < 4) ? (void*)(qk + (size_t)zi * QS) : (void*)(vv + (size_t)(zi - 4) * QS);
      a.storebf[zi] = (zi >= 4);
    }
    a.K = DIN; a.lda = DIN; a.ldb = DIN; a.ldc = DA;
    gemm_bt<f16, f16, 0, 128><<<dim3(DA / 128, NROWS / 128, 6), dim3(512), 0, stream>>>(a);
  }

  // 4. V -> Vt ([4096,512] -> [512][4096])
  transpose_b16<<<dim3(DA / 32, NROWS / 32, 2), dim3(32, 8), 0, stream>>>(
      vv, QS, vt, QS, NROWS, DA);

  // 5. P = exp(Q @ K^T), 128x256 tile: z=0: Q1@K2^T, z=1: Q2@K1^T (nt bf16 out)
  {
    GArgs<f16> a{};
    a.A[0] = qk + 0 * QS; a.B[0] = qk + 3 * QS; a.C[0] = P;
    a.A[1] = qk + 2 * QS; a.B[1] = qk + 1 * QS; a.C[1] = P + PS;
    a.K = DA; a.lda = DA; a.ldb = DA; a.ldc = NROWS;
    gemm_bt<f16, bf16, 1, 256><<<dim3(NROWS / 256, NROWS / 128, 2), dim3(512), 0, stream>>>(a);
  }

  // 6. PV split-K partials: z encodes (s = z>>1, pair = z&1)
  {
    GArgs<bf16> a{};
    for (int i = 0; i < 4; ++i) {
      int pair = i & 1, s = i >> 1;
      a.A[i] = P + (size_t)pair * PS;
      a.B[i] = vt + (size_t)(pair ^ 1) * QS;
      a.C[i] = pO + (size_t)i * QS;
      a.rsO[i] = prs + (size_t)i * NROWS;
      a.k0[i] = s * 2048;
    }
    a.K = 2048; a.lda = NROWS; a.ldb = NROWS; a.ldc = DA;
    gemm_bt<bf16, float, 2, 128><<<dim3(DA / 128, NROWS / 128, 4), dim3(512), 0, stream>>>(a);
  }

  // 7. merge partials -> mid (f16)
  merge_kernel<<<dim3((unsigned)(2 * QS / 1024)), dim3(256), 0, stream>>>(pO, prs, mid);

  // 8. out = mid @ Wo + bo (f32, nt)
  {
    GArgs<f16> a{};
    a.A[0] = mid;      a.C[0] = out;
    a.A[1] = mid + QS; a.C[1] = out + (size_t)NROWS * DIN;
    a.B[0] = a.B[1] = woT;
    a.bias[0] = a.bias[1] = bo;
    a.K = DA; a.lda = DA; a.ldb = DA; a.ldc = DIN;
    gemm_bt<f16, float, 3, 128><<<dim3(DIN / 128, NROWS / 128, 2), dim3(512), 0, stream>>>(a);
  }
}

// Round 7
// 211.755 us; speedup vs baseline: 1.0896x; 1.0878x over previous
//
#include <hip/hip_runtime.h>

typedef __bf16 bf16;
typedef _Float16 f16;
typedef __bf16 bf16x8 __attribute__((ext_vector_type(8)));
typedef _Float16 f16x8 __attribute__((ext_vector_type(8)));
typedef _Float16 f16x4 __attribute__((ext_vector_type(4)));
typedef float f32x4 __attribute__((ext_vector_type(4)));

#define NROWS 4096
#define DIN 1024
#define DA 512

template <typename T> struct V8;
template <> struct V8<f16> { using type = f16x8; };
template <> struct V8<bf16> { using type = bf16x8; };

__device__ __forceinline__ f32x4 mfma16(f16x8 a, f16x8 b, f32x4 c) {
  return __builtin_amdgcn_mfma_f32_16x16x32_f16(a, b, c, 0, 0, 0);
}
__device__ __forceinline__ f32x4 mfma16(bf16x8 a, bf16x8 b, f32x4 c) {
  return __builtin_amdgcn_mfma_f32_16x16x32_bf16(a, b, c, 0, 0, 0);
}

__device__ __forceinline__ void gload_lds16(const void* g, void* l) {
  __builtin_amdgcn_global_load_lds((const __attribute__((address_space(1))) void*)g,
                                   (__attribute__((address_space(3))) void*)l, 16, 0, 0);
}

// ---------------- prep kernels ----------------

__global__ void cast_kernel(const float* __restrict__ s1, const float* __restrict__ s2,
                            f16* __restrict__ d1, f16* __restrict__ d2, int n) {
  const float* s = blockIdx.z ? s2 : s1;
  f16* d = blockIdx.z ? d2 : d1;
  int i = (blockIdx.x * blockDim.x + threadIdx.x) * 4;
  if (i < n) {
    float4 v = *(const float4*)(s + i);
    f16x4 o;
    o[0] = (f16)v.x; o[1] = (f16)v.y; o[2] = (f16)v.z; o[3] = (f16)v.w;
    *(f16x4*)(d + i) = o;
  }
}

// dst[c][r] = (f16) src[r][c]
__global__ void transpose_f32(const float* __restrict__ w0, const float* __restrict__ w1,
                              const float* __restrict__ w2, f16* __restrict__ dst,
                              size_t dstride, int rows, int cols) {
  const float* s = blockIdx.z == 0 ? w0 : (blockIdx.z == 1 ? w1 : w2);
  f16* d = dst + (size_t)blockIdx.z * dstride;
  __shared__ float tile[32][33];
  int bc = blockIdx.x * 32, br = blockIdx.y * 32;
  int tx = threadIdx.x, ty = threadIdx.y;
  for (int i = ty; i < 32; i += 8)
    tile[i][tx] = s[(size_t)(br + i) * cols + bc + tx];
  __syncthreads();
  for (int i = ty; i < 32; i += 8)
    d[(size_t)(bc + i) * rows + br + tx] = (f16)tile[tx][i];
}

// bf16 [rows,cols] -> bf16 [cols][rows]
__global__ void transpose_b16(const bf16* __restrict__ src, size_t sstride,
                              bf16* __restrict__ dst, size_t dstride, int rows, int cols) {
  const bf16* s = src + (size_t)blockIdx.z * sstride;
  bf16* d = dst + (size_t)blockIdx.z * dstride;
  __shared__ float tile[32][33];
  int bc = blockIdx.x * 32, br = blockIdx.y * 32;
  int tx = threadIdx.x, ty = threadIdx.y;
  for (int i = ty; i < 32; i += 8)
    tile[i][tx] = (float)s[(size_t)(br + i) * cols + bc + tx];
  __syncthreads();
  for (int i = ty; i < 32; i += 8)
    d[(size_t)(bc + i) * rows + br + tx] = (bf16)tile[tx][i];
}

// merge split-K PV partials: mid = (pO[z]+pO[2+z]) / (rs[z]+rs[2+z]), f16
__global__ void merge_kernel(const float* __restrict__ pO, const float* __restrict__ prs,
                             f16* __restrict__ mid) {
  const size_t QS = (size_t)NROWS * DA;
  size_t e = ((size_t)blockIdx.x * blockDim.x + threadIdx.x) * 4;
  int z = (int)(e / QS);
  size_t rem = e - (size_t)z * QS;
  int row = (int)(rem / DA);
  float4 a = *(const float4*)(pO + (size_t)z * QS + rem);
  float4 b = *(const float4*)(pO + (size_t)(2 + z) * QS + rem);
  float rs = prs[z * NROWS + row] + prs[(2 + z) * NROWS + row];
  float inv = 1.0f / rs;
  f16x4 o;
  o[0] = (f16)((a.x + b.x) * inv);
  o[1] = (f16)((a.y + b.y) * inv);
  o[2] = (f16)((a.z + b.z) * inv);
  o[3] = (f16)((a.w + b.w) * inv);
  *(f16x4*)(mid + (size_t)z * QS + rem) = o;
}

// ---------------- 8-phase 256x256 QK kernel ----------------
// P[z] = exp(Qz @ Kz'^T). BM=BN=256, BK=64, 8 waves (2M x 4N), M-interleaved
// wave frags (phase p consumes global A-rows p*64..p*64+63). Double-buffered
// LDS (128 KB), 1-tile-ahead staging [B0,B1,A0,A1] one half per phase,
// counted vmcnt(2)@ph3 / vmcnt(4)@ph1. XOR swizzle chunk^=(row&7) via
// inverse-swizzled global source. Raw s_barrier; never __syncthreads.

__global__ __launch_bounds__(512, 1) void qk8(
    const f16* __restrict__ q1, const f16* __restrict__ k2,
    const f16* __restrict__ q2, const f16* __restrict__ k1,
    bf16* __restrict__ Pout) {
  __shared__ __align__(16) char smem[131072];
  const int z = blockIdx.z;
  const f16* __restrict__ A = z ? q2 : q1;
  const f16* __restrict__ B = z ? k1 : k2;
  bf16* __restrict__ C = Pout + (size_t)z * ((size_t)NROWS * NROWS);

  // T1 XCD swizzle within z (nwg = 256, gx = 16)
  int blkM, blkN;
  {
    const int lin = blockIdx.y * 16 + blockIdx.x;
    const int nl = (lin & 7) * 32 + (lin >> 3);
    blkN = nl & 15;
    blkM = nl >> 4;
  }

  const int tid = threadIdx.x;
  const int w = tid >> 6, lane = tid & 63;
  const int wm = w & 1, wn = w >> 1;  // 2M x 4N
  const int lr = lane & 15, lh = lane >> 4;

  const f16* Abase = A + (size_t)blkM * 256 * DA;
  const f16* Bbase = B + (size_t)blkN * 256 * DA;

  f32x4 acc[8][4] = {};
  f16x8 bfr[4][2];
  f16x8 af[2][2];

  // stage one 128-row half (op 0 = A, 1 = B) of K-tile at col kt into buf
#define STAGE(buf, op, hf, kt)                                                  \
  {                                                                             \
    char* dst_ = smem + (buf)*65536 + (op)*32768 + (hf)*16384;                  \
    const f16* src_ = ((op) ? Bbase : Abase) + (size_t)((hf)*128) * DA + (kt);  \
    _Pragma("unroll")                                                           \
    for (int i_ = 0; i_ < 2; ++i_) {                                            \
      int cidx_ = i_ * 512 + tid;                                               \
      int row_ = cidx_ >> 3, cc_ = cidx_ & 7;                                   \
      gload_lds16(src_ + (size_t)row_ * DA + ((cc_ ^ (row_ & 7)) << 3),         \
                  dst_ + cidx_ * 16);                                           \
    }                                                                           \
  }

  // ds_read A-frags for phase p: wave frag f = p*2+fi -> global row-frag f*2+wm
#define LDA_PHASE(buf, p)                                                       \
  {                                                                             \
    char* Ab_ = smem + (buf)*65536;                                             \
    _Pragma("unroll")                                                           \
    for (int fi_ = 0; fi_ < 2; ++fi_) {                                         \
      int row_ = (((p)*2 + fi_) * 2 + wm) * 16 + lr;                            \
      _Pragma("unroll")                                                         \
      for (int kk_ = 0; kk_ < 2; ++kk_) {                                       \
        int cc_ = (kk_ * 4 + lh) ^ (row_ & 7);                                  \
        af[fi_][kk_] = *(const f16x8*)(Ab_ + row_ * 128 + cc_ * 16);            \
      }                                                                         \
    }                                                                           \
  }

#define LDB_ALL(buf)                                                            \
  {                                                                             \
    char* Bb_ = smem + (buf)*65536 + 32768;                                     \
    _Pragma("unroll")                                                           \
    for (int n_ = 0; n_ < 4; ++n_) {                                            \
      int row_ = wn * 64 + n_ * 16 + lr;                                        \
      _Pragma("unroll")                                                         \
      for (int kk_ = 0; kk_ < 2; ++kk_) {                                       \
        int cc_ = (kk_ * 4 + lh) ^ (row_ & 7);                                  \
        bfr[n_][kk_] = *(const f16x8*)(Bb_ + row_ * 128 + cc_ * 16);            \
      }                                                                         \
    }                                                                           \
  }

#define MFMA_PHASE(p)                                                           \
  _Pragma("unroll")                                                             \
  for (int fi_ = 0; fi_ < 2; ++fi_) {                                           \
    _Pragma("unroll")                                                           \
    for (int n_ = 0; n_ < 4; ++n_) {                                            \
      _Pragma("unroll")                                                         \
      for (int kk_ = 0; kk_ < 2; ++kk_)                                         \
        acc[(p)*2 + fi_][n_] = mfma16(af[fi_][kk_], bfr[n_][kk_],               \
                                      acc[(p)*2 + fi_][n_]);                    \
    }                                                                           \
  }

#define BAR() __builtin_amdgcn_s_barrier()
#define LGK0()                                          \
  asm volatile("s_waitcnt lgkmcnt(0)" ::: "memory");    \
  __builtin_amdgcn_sched_barrier(0)

  // prologue: tile 0 halves B0,B1,A0,A1 into buf 0
  STAGE(0, 1, 0, 0); STAGE(0, 1, 1, 0); STAGE(0, 0, 0, 0); STAGE(0, 0, 1, 0);
  asm volatile("s_waitcnt vmcnt(2)" ::: "memory");  // B0,B1,A0 landed; A1 in flight
  BAR();

  for (int t = 0; t < 8; ++t) {
    const int cur = t & 1, nxt = cur ^ 1;
    const int ktn = (t + 1) * 64;
    const bool st = (t < 7);
    // ---- ph0 ----
    if (st) STAGE(nxt, 1, 0, ktn);
    LDB_ALL(cur);
    LDA_PHASE(cur, 0);
    BAR();
    LGK0();
    __builtin_amdgcn_s_setprio(1);
    MFMA_PHASE(0);
    __builtin_amdgcn_s_setprio(0);
    BAR();
    // ---- ph1 ----
    if (st) STAGE(nxt, 1, 1, ktn);
    LDA_PHASE(cur, 1);
    BAR();
    LGK0();
    __builtin_amdgcn_s_setprio(1);
    MFMA_PHASE(1);
    __builtin_amdgcn_s_setprio(0);
    if (st) { asm volatile("s_waitcnt vmcnt(4)" ::: "memory"); }  // A1(t) landed
    else    { asm volatile("s_waitcnt vmcnt(0)" ::: "memory"); }
    BAR();
    // ---- ph2 ----
    if (st) STAGE(nxt, 0, 0, ktn);
    LDA_PHASE(cur, 2);
    BAR();
    LGK0();
    __builtin_amdgcn_s_setprio(1);
    MFMA_PHASE(2);
    __builtin_amdgcn_s_setprio(0);
    BAR();
    // ---- ph3 ----
    if (st) STAGE(nxt, 0, 1, ktn);
    LDA_PHASE(cur, 3);
    BAR();
    LGK0();
    __builtin_amdgcn_s_setprio(1);
    MFMA_PHASE(3);
    __builtin_amdgcn_s_setprio(0);
    if (st) { asm volatile("s_waitcnt vmcnt(2)" ::: "memory"); }  // B0,B1,A0(t+1) landed
    BAR();
  }

  // epilogue: exp + bf16 store (plain, cached)
  const int row0 = blkM * 256, col0 = blkN * 256 + wn * 64;
#pragma unroll
  for (int f = 0; f < 8; ++f) {
#pragma unroll
    for (int n = 0; n < 4; ++n) {
#pragma unroll
      for (int rr = 0; rr < 4; ++rr) {
        int row = row0 + (f * 2 + wm) * 16 + lh * 4 + rr;
        int col = col0 + n * 16 + lr;
        C[(size_t)row * NROWS + col] = (bf16)__expf(acc[f][n][rr]);
      }
    }
  }
#undef STAGE
#undef LDA_PHASE
#undef LDB_ALL
#undef MFMA_PHASE
#undef BAR
#undef LGK0
}

// ---------------- GEMM (proj / PV / out) ----------------
// C = A @ Bt^T, 128x128 tile, BK=64, 8 waves (2x4, each 64x32), T1 swizzle.
// EPI 0: +bias, store f16/bf16 per storebf[z]
// EPI 2: split-K partial: store f32 acc + partial rowsum
// EPI 3: +bias, store f32

template <typename TIN>
struct GArgs {
  const TIN* A[6];
  const TIN* B[6];
  const float* bias[6];
  void* C[6];
  float* rsO[6];
  int k0[6];
  int storebf[6];
  int K, lda, ldb, ldc;
};

template <typename TIN, typename TOUT, int EPI>
__global__ __launch_bounds__(512) void gemm_bt(GArgs<TIN> args) {
  using vec8 = typename V8<TIN>::type;
  __shared__ __align__(16) TIN As[128 * 64];
  __shared__ __align__(16) TIN Bs[128 * 64];

  const int z = blockIdx.z;
  const TIN* __restrict__ Ag = args.A[z];
  const TIN* __restrict__ Bg = args.B[z];
  const float* __restrict__ bias = args.bias[z];
  void* Cg = args.C[z];
  const int K = args.K, k0 = args.k0[z];
  const int lda = args.lda, ldb = args.ldb, ldc = args.ldc;

  int blkM, blkN;
  {
    const int gx = gridDim.x;
    const int nwg = gx * gridDim.y;
    const int lin = blockIdx.y * gx + blockIdx.x;
    if ((nwg & 7) == 0) {
      const int q = nwg >> 3;
      const int nl = (lin & 7) * q + (lin >> 3);
      blkN = nl % gx;
      blkM = nl / gx;
    } else {
      blkN = blockIdx.x;
      blkM = blockIdx.y;
    }
  }

  const int tid = threadIdx.x;
  const int w = tid >> 6, lane = tid & 63;
  const int wr = w >> 2, wc = w & 3;
  const int lrow = lane & 15, lhi = lane >> 4;

  const TIN* Abase = Ag + (size_t)blkM * 128 * lda;
  const TIN* Bbase = Bg + (size_t)blkN * 128 * ldb;

  f32x4 acc[4][2] = {};
  f32x4 rs[4] = {};
  vec8 ones;
  if (EPI == 2) {
#pragma unroll
    for (int i = 0; i < 8; ++i) ones[i] = (TIN)1.0f;
  }

  for (int kt = k0; kt < k0 + K; kt += 64) {
#pragma unroll
    for (int it = 0; it < 2; ++it) {
      int cidx = (it * 8 + w) * 64 + lane;
      int row = cidx >> 3;
      int col = (cidx & 7) << 3;
      gload_lds16(Abase + (size_t)row * lda + kt + col, (char*)As + (size_t)cidx * 16);
    }
#pragma unroll
    for (int it = 0; it < 2; ++it) {
      int cidx = (it * 8 + w) * 64 + lane;
      int row = cidx >> 3;
      int col = (cidx & 7) << 3;
      gload_lds16(Bbase + (size_t)row * ldb + kt + col, (char*)Bs + (size_t)cidx * 16);
    }
    __syncthreads();

    vec8 af[4][2], bfr[2][2];
#pragma unroll
    for (int m = 0; m < 4; ++m)
#pragma unroll
      for (int kk = 0; kk < 2; ++kk)
        af[m][kk] = *(const vec8*)&As[(wr * 64 + m * 16 + lrow) * 64 + kk * 32 + lhi * 8];
#pragma unroll
    for (int n = 0; n < 2; ++n)
#pragma unroll
      for (int kk = 0; kk < 2; ++kk)
        bfr[n][kk] = *(const vec8*)&Bs[(wc * 32 + n * 16 + lrow) * 64 + kk * 32 + lhi * 8];

#pragma unroll
    for (int m = 0; m < 4; ++m)
#pragma unroll
      for (int n = 0; n < 2; ++n)
#pragma unroll
        for (int kk = 0; kk < 2; ++kk)
          acc[m][n] = mfma16(af[m][kk], bfr[n][kk], acc[m][n]);

    if (EPI == 2 && wc == 0) {
#pragma unroll
      for (int m = 0; m < 4; ++m)
#pragma unroll
        for (int kk = 0; kk < 2; ++kk)
          rs[m] = mfma16(af[m][kk], ones, rs[m]);
    }
    __syncthreads();
  }

  const int row0 = blkM * 128 + wr * 64;
  const int col0 = blkN * 128 + wc * 32;
  const int sbf = args.storebf[z];
#pragma unroll
  for (int m = 0; m < 4; ++m) {
#pragma unroll
    for (int n = 0; n < 2; ++n) {
#pragma unroll
      for (int r = 0; r < 4; ++r) {
        int row = row0 + m * 16 + lhi * 4 + r;
        int col = col0 + n * 16 + lrow;
        float v = acc[m][n][r];
        if (EPI == 0) {
          if (sbf)
            ((bf16*)Cg)[(size_t)row * ldc + col] = (bf16)(v + bias[col]);
          else
            ((f16*)Cg)[(size_t)row * ldc + col] = (f16)(v + bias[col]);
        } else if (EPI == 2) {
          ((float*)Cg)[(size_t)row * ldc + col] = v;
        } else {
          ((float*)Cg)[(size_t)row * ldc + col] = v + bias[col];
        }
      }
    }
  }
  if (EPI == 2 && wc == 0 && lrow == 0) {
    float* rsO = args.rsO[z];
#pragma unroll
    for (int m = 0; m < 4; ++m)
#pragma unroll
      for (int r = 0; r < 4; ++r)
        rsO[row0 + m * 16 + lhi * 4 + r] = rs[m][r];
  }
}

// ---------------- launch ----------------

extern "C" void kernel_launch(void* const* d_in, const int* in_sizes, int n_in,
                              void* d_out, int out_size, void* d_ws, size_t ws_size,
                              hipStream_t stream) {
  const float* in1 = (const float*)d_in[0];
  const float* in2 = (const float*)d_in[1];
  const float* Wq = (const float*)d_in[2];
  const float* bq = (const float*)d_in[3];
  const float* Wk = (const float*)d_in[4];
  const float* bk = (const float*)d_in[5];
  const float* Wv = (const float*)d_in[6];
  const float* bv = (const float*)d_in[7];
  const float* Wo = (const float*)d_in[8];
  const float* bo = (const float*)d_in[9];
  float* out = (float*)d_out;

  const size_t IN_E = (size_t)NROWS * DIN;   // 4M
  const size_t WT_E = (size_t)DA * DIN;      // 512K
  const size_t QS = (size_t)NROWS * DA;      // 2M
  const size_t PS = (size_t)NROWS * NROWS;   // 16M

  f16* qk = (f16*)d_ws;                      // 16 MB (dead after QK)
  f16* in_hf = qk + 4 * QS;                  // 16 MB (dead after proj)
  bf16* vv = (bf16*)(in_hf + 2 * IN_E);      // 8 MB (dead after transpose)
  f16* wt = (f16*)(vv + 2 * QS);             // 3 MB
  f16* woT = wt + 3 * WT_E;                  // 1 MB
  bf16* vt = (bf16*)(woT + WT_E);            // 8 MB
  bf16* P = vt + 2 * QS;                     // 64 MB
  f16* mid = (f16*)(P + 2 * PS);             // 8 MB
  float* pO = (float*)d_ws;                  // 32 MB, aliases qk+in_hf
  float* prs = (float*)vv;                   // 64 KB, aliases vv

  // 1. cast inputs to fp16
  cast_kernel<<<dim3((unsigned)(IN_E / 1024), 1, 2), dim3(256), 0, stream>>>(
      in1, in2, in_hf, in_hf + IN_E, (int)IN_E);

  // 2. transpose-cast weights
  transpose_f32<<<dim3(DA / 32, DIN / 32, 3), dim3(32, 8), 0, stream>>>(
      Wq, Wk, Wv, wt, WT_E, DIN, DA);
  transpose_f32<<<dim3(DIN / 32, DA / 32, 1), dim3(32, 8), 0, stream>>>(
      Wo, Wo, Wo, woT, 0, DA, DIN);

  // 3. projections, z = Q1,K1,Q2,K2,V1,V2 (V stored bf16)
  {
    GArgs<f16> a{};
    const float* bs[3] = {bq, bk, bv};
    for (int zi = 0; zi < 6; ++zi) {
      int which = (zi < 4) ? (zi & 1) : 2;
      int src = (zi < 4) ? (zi >> 1) : (zi - 4);
      a.A[zi] = in_hf + (size_t)src * IN_E;
      a.B[zi] = wt + (size_t)which * WT_E;
      a.bias[zi] = bs[which];
      a.C[zi] = (zi < 4) ? (void*)(qk + (size_t)zi * QS) : (void*)(vv + (size_t)(zi - 4) * QS);
      a.storebf[zi] = (zi >= 4);
    }
    a.K = DIN; a.lda = DIN; a.ldb = DIN; a.ldc = DA;
    gemm_bt<f16, f16, 0><<<dim3(DA / 128, NROWS / 128, 6), dim3(512), 0, stream>>>(a);
  }

  // 4. V -> Vt ([4096,512] -> [512][4096])
  transpose_b16<<<dim3(DA / 32, NROWS / 32, 2), dim3(32, 8), 0, stream>>>(
      vv, QS, vt, QS, NROWS, DA);

  // 5. P = exp(Q @ K^T): 8-phase 256x256 kernel
  qk8<<<dim3(16, 16, 2), dim3(512), 0, stream>>>(
      qk + 0 * QS, qk + 3 * QS, qk + 2 * QS, qk + 1 * QS, P);

  // 6. PV split-K partials: z encodes (s = z>>1, pair = z&1)
  {
    GArgs<bf16> a{};
    for (int i = 0; i < 4; ++i) {
      int pair = i & 1, s = i >> 1;
      a.A[i] = P + (size_t)pair * PS;
      a.B[i] = vt + (size_t)(pair ^ 1) * QS;
      a.C[i] = pO + (size_t)i * QS;
      a.rsO[i] = prs + (size_t)i * NROWS;
      a.k0[i] = s * 2048;
    }
    a.K = 2048; a.lda = NROWS; a.ldb = NROWS; a.ldc = DA;
    gemm_bt<bf16, float, 2><<<dim3(DA / 128, NROWS / 128, 4), dim3(512), 0, stream>>>(a);
  }

  // 7. merge partials -> mid (f16)
  merge_kernel<<<dim3((unsigned)(2 * QS / 1024)), dim3(256), 0, stream>>>(pO, prs, mid);

  // 8. out = mid @ Wo + bo (f32)
  {
    GArgs<f16> a{};
    a.A[0] = mid;      a.C[0] = out;
    a.A[1] = mid + QS; a.C[1] = out + (size_t)NROWS * DIN;
    a.B[0] = a.B[1] = woT;
    a.bias[0] = a.bias[1] = bo;
    a.K = DA; a.lda = DA; a.ldb = DA; a.ldc = DIN;
    gemm_bt<f16, float, 3><<<dim3(DIN / 128, NROWS / 128, 2), dim3(512), 0, stream>>>(a);
  }
}